// Round 8
// baseline (1020.898 us; speedup 1.0000x reference)
//
#include <hip/hip_runtime.h>
#include <hip/hip_cooperative_groups.h>
#include <math.h>

namespace cg = cooperative_groups;

// ---------- helpers ----------
__device__ __forceinline__ ushort f2bf(float f) {
    unsigned int u = __float_as_uint(f);
    u += 0x7FFFu + ((u >> 16) & 1u);   // round-to-nearest-even
    return (ushort)(u >> 16);
}

typedef __attribute__((address_space(1))) const unsigned int guint;
typedef __attribute__((address_space(3))) unsigned int luint;
__device__ __forceinline__ void gload_lds16(const void* g, void* l) {
    __builtin_amdgcn_global_load_lds((guint*)g, (luint*)l, 16, 0, 0);
}

using bfrag = __attribute__((ext_vector_type(8))) short;   // 8 bf16 = 4 VGPR
using f4    = __attribute__((ext_vector_type(4))) float;

__device__ __forceinline__ void bf8_to_f(uint4 v, float* o) {
    unsigned int u[4] = {v.x, v.y, v.z, v.w};
    #pragma unroll
    for (int i = 0; i < 4; ++i) {
        o[2 * i]     = __uint_as_float(u[i] << 16);
        o[2 * i + 1] = __uint_as_float(u[i] & 0xFFFF0000u);
    }
}

struct MegaArgs {
    const float* x[4];
    const float* wgt[4];
    const float* bia[4];
    const float* owt[4];    // [0] unused
    const float* obv[4];    // [0] unused
    ushort* wbf[4];
    ushort* owbf[4];        // [0] unused
    ushort* cols;
    ushort* xsb[4];
    float*  offbuf[4];      // [0] unused
    ushort* zeros;
    float*  zbase;
    int     z4;
    float*  out[4];
};

// ---------- stage: weight cvt+reorder w[m][c][r] -> wq[m][r*256+c] bf16 ----------
__device__ __forceinline__ void st_cvt(const MegaArgs& a, int vb) {
    int t = vb / 288, bxi = vb - t * 288;
    int M = (t < 4) ? 256 : 27;
    const float* src = (t < 4) ? a.wgt[t] : a.owt[t - 3];
    ushort* dst = (t < 4) ? a.wbf[t] : a.owbf[t - 3];
    int idx = bxi * 256 + threadIdx.x;
    if (idx < M * 288) {
        int m = idx / 288, rem = idx - m * 288;
        int r = rem >> 5, c8 = rem & 31;
        const float* s = src + ((size_t)(m * 256 + c8 * 8)) * 9 + r;
        ushort vals[8];
        #pragma unroll
        for (int j = 0; j < 8; ++j) vals[j] = f2bf(s[j * 9]);
        *(uint4*)&dst[(size_t)m * 2304 + r * 256 + c8 * 8] = *(uint4*)vals;
    }
}

// ---------- stage: bias prefill (levels 1..3) + zero offbuf/zeropage ----------
__device__ __forceinline__ void st_fill(const MegaArgs& a, int vb) {
    int y = vb / 1152, bxi = vb - y * 1152;
    int i = bxi * 256 + threadIdx.x;
    if (y < 3) {
        int HW = (y == 0) ? 2304 : (y == 1) ? 576 : 144;
        float* outp = a.out[y + 1];
        const float* bias = a.bia[y + 1];
        if (i < 128 * HW) {
            int e = i << 2;
            int m = (e / HW) & 255;
            float v = bias[m];
            *(float4*)&outp[e] = float4{v, v, v, v};
        }
    } else {
        if (i < a.z4) ((float4*)a.zbase)[i] = float4{0.f, 0.f, 0.f, 0.f};
    }
}

// ---------- stage: xs = NHWC bf16 of (x + up2(prev)) ----------
__device__ __forceinline__ void st_xs(char* smemc,
    const float* __restrict__ x, const float* __restrict__ prev,
    ushort* __restrict__ xs, int H, int W, int bx, int by, int bz)
{
    ushort (*tile)[72] = (ushort(*)[72])smemc;
    const int HW = H * W, W2 = W >> 1;
    int b = bz, c0 = by * 32, hw0 = bx * 64;
    const float* xb = x + ((size_t)b * 256 + c0) * HW;
    const float* pb = prev ? prev + ((size_t)b * 256 + c0) * (HW >> 2) : nullptr;

    int hwl = threadIdx.x & 63, cl0 = threadIdx.x >> 6;
    int hw = hw0 + hwl;
    bool ok = hw < HW;
    int hwc = ok ? hw : HW - 1;
    int h = hwc / W, w = hwc - h * W;
    int pidx = (h >> 1) * W2 + (w >> 1);
    #pragma unroll
    for (int p = 0; p < 8; ++p) {
        int cl = p * 4 + cl0;
        float v = 0.f;
        if (ok) {
            v = xb[(size_t)cl * HW + hw];
            if (pb) v += pb[(size_t)cl * (HW >> 2) + pidx];
        }
        tile[cl][hwl] = f2bf(v);
    }
    __syncthreads();
    int hwl2 = threadIdx.x >> 2, cc = (threadIdx.x & 3) * 8;
    int hw2 = hw0 + hwl2;
    if (hw2 < HW) {
        ushort vals[8];
        #pragma unroll
        for (int j = 0; j < 8; ++j) vals[j] = tile[cc + j][hwl2];
        *(uint4*)&xs[((size_t)b * HW + hw2) * 256 + c0 + cc] = *(uint4*)vals;
    }
    __syncthreads();   // protect LDS reuse across virtual blocks
}

// ---------- stage: offset conv (M=27 pad 32, split-K atomics, BK=32 dbuf) ----------
__device__ __forceinline__ void st_off(char* smemc,
    const ushort* __restrict__ A, const ushort* __restrict__ xs,
    const ushort* __restrict__ zeros, float* __restrict__ offbuf,
    int N, int H, int W, int ktiles, int bx, int by, int bz)
{
    ushort* As0 = (ushort*)smemc;            // [2][32*32]
    ushort* Bs0 = (ushort*)(smemc + 4096);   // [2][64*32]
    const int b = bz, n0 = bx * 64, kt0 = by * ktiles * 32;
    const int tid = threadIdx.x, lane = tid & 63, wvv = tid >> 6;
    const ushort* xb = xs + (size_t)b * N * 256;

    int n = n0 + (tid >> 2); if (n >= N) n = N - 1;
    int h = n / W, w = n - h * W;
    int kcc = (tid & 3) * 8;

    auto stage = [&](int kt, int bi) {
        int r = kt >> 8, c0k = kt & 255;
        int ry = r / 3 - 1, rx = r - (r / 3) * 3 - 1;
        if (tid < 128) {
            int row = tid >> 2; if (row > 26) row = 26;
            gload_lds16(A + (size_t)row * 2304 + kt + kcc,
                        (char*)(As0 + bi * 1024) + (size_t)(tid & ~63) * 16);
        }
        int ih = h + ry, iw = w + rx;
        const ushort* src = (ih >= 0 && ih < H && iw >= 0 && iw < W)
            ? xb + (((size_t)(ih * W + iw)) << 8) + c0k + kcc
            : zeros;
        gload_lds16(src, (char*)(Bs0 + bi * 2048) + (size_t)(tid & ~63) * 16);
    };

    f4 acc[2] = {};
    stage(kt0, 0);
    for (int kk = 0; kk < ktiles; ++kk) {
        __syncthreads();
        if (kk + 1 < ktiles) stage(kt0 + (kk + 1) * 32, (kk + 1) & 1);
        const ushort* as = As0 + (kk & 1) * 1024;
        const ushort* bs = Bs0 + (kk & 1) * 2048;
        bfrag bf = *(const bfrag*)&bs[(wvv * 16 + (lane & 15)) * 32 + (lane >> 4) * 8];
        bfrag a0 = *(const bfrag*)&as[(lane & 15) * 32 + (lane >> 4) * 8];
        bfrag a1 = *(const bfrag*)&as[(16 + (lane & 15)) * 32 + (lane >> 4) * 8];
        acc[0] = __builtin_amdgcn_mfma_f32_16x16x32_bf16(a0, bf, acc[0], 0, 0, 0);
        acc[1] = __builtin_amdgcn_mfma_f32_16x16x32_bf16(a1, bf, acc[1], 0, 0, 0);
    }
    __syncthreads();   // protect LDS reuse

    int nn = n0 + wvv * 16 + (lane & 15);
    if (nn < N) {
        #pragma unroll
        for (int mb = 0; mb < 2; ++mb)
            #pragma unroll
            for (int t = 0; t < 4; ++t) {
                int m = mb * 16 + (lane >> 4) * 4 + t;
                if (m < 27)
                    atomicAdd(&offbuf[((size_t)b * 27 + m) * N + nn], acc[mb][t]);
            }
    }
}

// ---------- stage: deformable sampling -> cols[b][hw][r*256+c] bf16 ----------
// block = 8 hw x 32 c-threads (8 ch each); geometry cached in LDS
__device__ __forceinline__ void st_samp(char* smemc,
    const ushort* __restrict__ xs, const float* __restrict__ off,
    const float* __restrict__ ob, ushort* __restrict__ cols,
    int H, int W, int bx, int bz)
{
    float4* gw = (float4*)smemc;             // [8*9]
    int4*   go = (int4*)(smemc + 8 * 9 * 16);
    const int HW = H * W;
    const int b = bz, hw0 = bx * 8, tid = threadIdx.x;
    const float* offb = off + (size_t)b * 27 * HW;
    const ushort* xb = xs + (size_t)b * HW * 256;

    if (tid < 72) {
        int hwl = tid / 9, k = tid - hwl * 9;
        int hw = hw0 + hwl; if (hw >= HW) hw = HW - 1;
        int h = hw / W, w = hw - h * W;
        float dy = offb[(size_t)(2 * k) * HW + hw] + ob[2 * k];
        float dx = offb[(size_t)(2 * k + 1) * HW + hw] + ob[2 * k + 1];
        float mv = offb[(size_t)(18 + k) * HW + hw] + ob[18 + k];
        float mk = 1.0f / (1.0f + __expf(-mv));
        float py = (float)h - 1.0f + (float)(k / 3) + dy;
        float px = (float)w - 1.0f + (float)(k % 3) + dx;
        float y0f = floorf(py), x0f = floorf(px);
        float wy = py - y0f, wx = px - x0f;
        int y0 = (int)y0f, x0i = (int)x0f;
        int y1 = y0 + 1, x1 = x0i + 1;
        bool vy0 = (y0 >= 0) & (y0 < H), vy1 = (y1 >= 0) & (y1 < H);
        bool vx0 = (x0i >= 0) & (x0i < W), vx1 = (x1 >= 0) & (x1 < W);
        float w00 = (1.f - wy) * (1.f - wx) * ((vy0 & vx0) ? mk : 0.f);
        float w01 = (1.f - wy) * wx        * ((vy0 & vx1) ? mk : 0.f);
        float w10 = wy * (1.f - wx)        * ((vy1 & vx0) ? mk : 0.f);
        float w11 = wy * wx                * ((vy1 & vx1) ? mk : 0.f);
        int cy0 = min(max(y0, 0), H - 1), cy1 = min(max(y1, 0), H - 1);
        int cx0 = min(max(x0i, 0), W - 1), cx1 = min(max(x1, 0), W - 1);
        gw[hwl * 9 + k] = float4{w00, w01, w10, w11};
        go[hwl * 9 + k] = int4{(cy0 * W + cx0) << 8, (cy0 * W + cx1) << 8,
                               (cy1 * W + cx0) << 8, (cy1 * W + cx1) << 8};
    }
    __syncthreads();

    int hwl = tid >> 5, cb = (tid & 31) * 8;
    int hw = hw0 + hwl;
    if (hw < HW) {
        ushort* colp = cols + ((size_t)b * HW + hw) * 2304 + cb;
        #pragma unroll
        for (int k = 0; k < 9; ++k) {
            float4 wv = gw[hwl * 9 + k];
            int4   ov = go[hwl * 9 + k];
            float f00[8], f01[8], f10[8], f11[8];
            bf8_to_f(*(const uint4*)(xb + ov.x + cb), f00);
            bf8_to_f(*(const uint4*)(xb + ov.y + cb), f01);
            bf8_to_f(*(const uint4*)(xb + ov.z + cb), f10);
            bf8_to_f(*(const uint4*)(xb + ov.w + cb), f11);
            unsigned int pk[4];
            #pragma unroll
            for (int t = 0; t < 4; ++t) {
                float lo = f00[2 * t] * wv.x + f01[2 * t] * wv.y +
                           f10[2 * t] * wv.z + f11[2 * t] * wv.w;
                float hi = f00[2 * t + 1] * wv.x + f01[2 * t + 1] * wv.y +
                           f10[2 * t + 1] * wv.z + f11[2 * t + 1] * wv.w;
                pk[t] = (unsigned int)f2bf(lo) | ((unsigned int)f2bf(hi) << 16);
            }
            *(uint4*)(colp + k * 256) = make_uint4(pk[0], pk[1], pk[2], pk[3]);
        }
    }
    __syncthreads();   // protect LDS reuse
}

// ---------- stage: bf16 MFMA GEMM, tile 128m x 64n, BK=64, XOR-swizzled ----------
template<bool IMPLICIT, bool SPLITK>
__device__ __forceinline__ void st_gemm(char* smemc,
    const ushort* __restrict__ A, const float* __restrict__ bias,
    const ushort* __restrict__ Bt, const ushort* __restrict__ zeros,
    float* __restrict__ outp, int N, int H, int W, int kchunk,
    int bx, int by, int bz)
{
    ushort* As = (ushort*)smemc;             // 128*64
    ushort* Bs = (ushort*)(smemc + 16384);   // 64*64
    const int b  = bz;
    const int m0 = (by & 1) * 128;
    const int kt0 = (by >> 1) * kchunk;
    const int n0 = bx * 64;
    const int tid  = threadIdx.x;
    const int lane = tid & 63;
    const int wv   = tid >> 6;
    const int wm = wv & 1, wn = wv >> 1;     // wave tile: 64m x 32n

    const ushort* Bb = IMPLICIT ? Bt + (size_t)b * N * 256
                                : Bt + (size_t)b * (size_t)N * 2304;

    const int sc8 = ((tid & 7) ^ ((tid >> 3) & 7)) * 8;
    const int srow = tid >> 3;               // 0..31
    int bn[2], bh[2], bw[2];
    #pragma unroll
    for (int j = 0; j < 2; ++j) {
        int n = n0 + j * 32 + srow; if (n >= N) n = N - 1;
        bn[j] = n; bh[j] = n / W; bw[j] = n - bh[j] * W;
    }

    auto stage = [&](int kt) {
        #pragma unroll
        for (int i = 0; i < 4; ++i) {
            gload_lds16(A + (size_t)(m0 + i * 32 + srow) * 2304 + kt + sc8,
                        (char*)As + (size_t)(i * 256 + (tid & ~63)) * 16);
        }
        if (!IMPLICIT) {
            #pragma unroll
            for (int j = 0; j < 2; ++j)
                gload_lds16(Bb + (size_t)bn[j] * 2304 + kt + sc8,
                            (char*)Bs + (size_t)(j * 256 + (tid & ~63)) * 16);
        } else {
            int r = kt >> 8, c0k = kt & 255;
            int ry = r / 3 - 1, rx = r - (r / 3) * 3 - 1;
            #pragma unroll
            for (int j = 0; j < 2; ++j) {
                int ih = bh[j] + ry, iw = bw[j] + rx;
                const ushort* src = (ih >= 0 && ih < H && iw >= 0 && iw < W)
                    ? Bb + (((size_t)(ih * W + iw)) << 8) + c0k + sc8
                    : zeros;
                gload_lds16(src, (char*)Bs + (size_t)(j * 256 + (tid & ~63)) * 16);
            }
        }
    };

    const int fq = (lane >> 4);
    const int fv = (lane & 7);
    f4 acc[4][2] = {};

    const int kend = kt0 + kchunk;
    for (int kt = kt0; kt < kend; kt += 64) {
        stage(kt);
        __syncthreads();
        bfrag af[2][4], bf[2][2];
        #pragma unroll
        for (int kh = 0; kh < 2; ++kh) {
            int ch = ((kh * 4 + fq) ^ fv) * 8;
            #pragma unroll
            for (int i = 0; i < 4; ++i)
                af[kh][i] = *(const bfrag*)&As[(wm * 64 + i * 16 + (lane & 15)) * 64 + ch];
            #pragma unroll
            for (int j = 0; j < 2; ++j)
                bf[kh][j] = *(const bfrag*)&Bs[(wn * 32 + j * 16 + (lane & 15)) * 64 + ch];
        }
        #pragma unroll
        for (int kh = 0; kh < 2; ++kh)
            #pragma unroll
            for (int i = 0; i < 4; ++i)
                #pragma unroll
                for (int j = 0; j < 2; ++j)
                    acc[i][j] = __builtin_amdgcn_mfma_f32_16x16x32_bf16(
                        af[kh][i], bf[kh][j], acc[i][j], 0, 0, 0);
        __syncthreads();
    }

    const int mb = m0 + wm * 64, nb = n0 + wn * 32;
    #pragma unroll
    for (int i = 0; i < 4; ++i) {
        int mrow = mb + i * 16 + (lane >> 4) * 4;
        #pragma unroll
        for (int j = 0; j < 2; ++j) {
            int n = nb + j * 16 + (lane & 15);
            if (n < N) {
                #pragma unroll
                for (int t = 0; t < 4; ++t) {
                    int m = mrow + t;
                    if (SPLITK)
                        atomicAdd(&outp[((size_t)b * 256 + m) * N + n], acc[i][j][t]);
                    else
                        outp[((size_t)b * 256 + m) * N + n] = acc[i][j][t] + bias[m];
                }
            }
        }
    }
}

// ---------- the cooperative mega-kernel ----------
__global__ __launch_bounds__(256, 2) void mega(MegaArgs a) {
    __shared__ __align__(16) char smem[24576];
    cg::grid_group grid = cg::this_grid();
    const int G = gridDim.x, g0 = blockIdx.x;

    // S0: weight cvt (2016) + prefill/zero (4608) + xs3 (48)
    for (int v = g0; v < 6672; v += G) {
        if (v < 2016) st_cvt(a, v);
        else if (v < 6624) st_fill(a, v - 2016);
        else { int u = v - 6624; st_xs(smem, a.x[3], nullptr, a.xsb[3], 12, 12, u % 3, (u / 3) & 7, u / 24); }
    }
    grid.sync();

    // ---- level 3 (H=12, HW=144)
    for (int v = g0; v < 144; v += G)
        st_off(smem, a.owbf[3], a.xsb[3], a.zeros, a.offbuf[3], 144, 12, 12, 3, v % 3, (v / 3) % 24, v / 72);
    grid.sync();
    for (int v = g0; v < 36; v += G)
        st_samp(smem, a.xsb[3], a.offbuf[3], a.obv[3], a.cols, 12, 12, v % 18, v / 18);
    grid.sync();
    for (int v = g0; v < 72; v += G)
        st_gemm<false, true>(smem, a.wbf[3], a.bia[3], a.cols, a.zeros, a.out[3], 144, 12, 12, 384, v % 3, (v / 3) % 12, v / 36);
    grid.sync();
    for (int v = g0; v < 144; v += G)
        st_xs(smem, a.x[2], a.out[3], a.xsb[2], 24, 24, v % 9, (v / 9) % 8, v / 72);
    grid.sync();

    // ---- level 2 (H=24, HW=576)
    for (int v = g0; v < 216; v += G)
        st_off(smem, a.owbf[2], a.xsb[2], a.zeros, a.offbuf[2], 576, 24, 24, 6, v % 9, (v / 9) % 12, v / 108);
    grid.sync();
    for (int v = g0; v < 144; v += G)
        st_samp(smem, a.xsb[2], a.offbuf[2], a.obv[2], a.cols, 24, 24, v % 72, v / 72);
    grid.sync();
    for (int v = g0; v < 144; v += G)
        st_gemm<false, true>(smem, a.wbf[2], a.bia[2], a.cols, a.zeros, a.out[2], 576, 24, 24, 576, v % 9, (v / 9) % 8, v / 72);
    grid.sync();
    for (int v = g0; v < 576; v += G)
        st_xs(smem, a.x[1], a.out[2], a.xsb[1], 48, 48, v % 36, (v / 36) % 8, v / 288);
    grid.sync();

    // ---- level 1 (H=48, HW=2304)
    for (int v = g0; v < 576; v += G)
        st_off(smem, a.owbf[1], a.xsb[1], a.zeros, a.offbuf[1], 2304, 48, 48, 9, v % 36, (v / 36) % 8, v / 288);
    grid.sync();
    for (int v = g0; v < 576; v += G)
        st_samp(smem, a.xsb[1], a.offbuf[1], a.obv[1], a.cols, 48, 48, v % 288, v / 288);
    grid.sync();
    for (int v = g0; v < 288; v += G)
        st_gemm<false, true>(smem, a.wbf[1], a.bia[1], a.cols, a.zeros, a.out[1], 2304, 48, 48, 1152, v % 36, (v / 36) % 4, v / 144);
    grid.sync();
    for (int v = g0; v < 2304; v += G)
        st_xs(smem, a.x[0], a.out[1], a.xsb[0], 96, 96, v % 144, (v / 144) % 8, v / 1152);
    grid.sync();

    // ---- level 0 (H=96, HW=9216): implicit NHWC GEMM, direct bias write
    for (int v = g0; v < 576; v += G)
        st_gemm<true, false>(smem, a.wbf[0], a.bia[0], a.xsb[0], a.zeros, a.out[0], 9216, 96, 96, 2304, v % 144, (v / 144) % 2, v / 288);
}

// ---------- host launch ----------
extern "C" void kernel_launch(void* const* d_in, const int* in_sizes, int n_in,
                              void* d_out, int out_size, void* d_ws, size_t ws_size,
                              hipStream_t stream)
{
    const int B = 2;
    const int HWs[4] = {96 * 96, 48 * 48, 24 * 24, 12 * 12};

    MegaArgs a;
    a.x[0] = (const float*)d_in[0];  a.x[1] = (const float*)d_in[1];
    a.x[2] = (const float*)d_in[2];  a.x[3] = (const float*)d_in[3];
    a.wgt[0] = (const float*)d_in[4];  a.wgt[1] = (const float*)d_in[6];
    a.wgt[2] = (const float*)d_in[8];  a.wgt[3] = (const float*)d_in[10];
    a.bia[0] = (const float*)d_in[5];  a.bia[1] = (const float*)d_in[7];
    a.bia[2] = (const float*)d_in[9];  a.bia[3] = (const float*)d_in[11];
    a.owt[0] = nullptr;                a.owt[1] = (const float*)d_in[12];
    a.owt[2] = (const float*)d_in[14]; a.owt[3] = (const float*)d_in[16];
    a.obv[0] = nullptr;                a.obv[1] = (const float*)d_in[13];
    a.obv[2] = (const float*)d_in[15]; a.obv[3] = (const float*)d_in[17];

    float* out = (float*)d_out;
    a.out[0] = out;
    a.out[1] = a.out[0] + (size_t)B * 256 * HWs[0];
    a.out[2] = a.out[1] + (size_t)B * 256 * HWs[1];
    a.out[3] = a.out[2] + (size_t)B * 256 * HWs[2];

    // ---- ws carve (256B aligned)
    char* ws = (char*)d_ws;
    size_t off = 0;
    auto carve = [&](size_t bytes) { void* p = ws + off; off = (off + bytes + 255) & ~(size_t)255; return p; };
    for (int i = 0; i < 4; ++i) a.wbf[i] = (ushort*)carve((size_t)256 * 2304 * 2);
    a.owbf[0] = nullptr;
    for (int i = 1; i < 4; ++i) a.owbf[i] = (ushort*)carve((size_t)27 * 2304 * 2);
    a.cols = (ushort*)carve((size_t)B * HWs[1] * 2304 * 2);   // max: level 1
    for (int i = 0; i < 4; ++i) a.xsb[i] = (ushort*)carve((size_t)B * 256 * HWs[i] * 2);
    int offElems = B * 27 * (HWs[1] + HWs[2] + HWs[3]);
    a.zbase = (float*)carve((size_t)offElems * 4 + 1024);
    a.zeros = (ushort*)(a.zbase + offElems);   // 1 KB zero page
    a.z4 = (offElems * 4 + 1024) / 16;
    a.offbuf[0] = nullptr;
    a.offbuf[1] = a.zbase;
    a.offbuf[2] = a.zbase + (size_t)B * 27 * HWs[1];
    a.offbuf[3] = a.zbase + (size_t)B * 27 * (HWs[1] + HWs[2]);

    // single cooperative launch: 512 blocks (2/CU co-resident guaranteed:
    // launch_bounds(256,2) caps VGPR<=256; LDS 24.5KB*2 < 160KB)
    void* kargs[] = { (void*)&a };
    hipLaunchCooperativeKernel((const void*)mega, dim3(512), dim3(256),
                               kargs, 0, stream);
}

// Round 9
// 285.956 us; speedup vs baseline: 3.5701x; 3.5701x over previous
//
#include <hip/hip_runtime.h>
#include <math.h>

// ---------- helpers ----------
__device__ __forceinline__ ushort f2bf(float f) {
    unsigned int u = __float_as_uint(f);
    u += 0x7FFFu + ((u >> 16) & 1u);   // round-to-nearest-even
    return (ushort)(u >> 16);
}

typedef __attribute__((address_space(1))) const unsigned int guint;
typedef __attribute__((address_space(3))) unsigned int luint;
__device__ __forceinline__ void gload_lds16(const void* g, void* l) {
    __builtin_amdgcn_global_load_lds((guint*)g, (luint*)l, 16, 0, 0);
}

using bfrag = __attribute__((ext_vector_type(8))) short;   // 8 bf16 = 4 VGPR
using f4    = __attribute__((ext_vector_type(4))) float;

__device__ __forceinline__ void bf8_to_f(uint4 v, float* o) {
    unsigned int u[4] = {v.x, v.y, v.z, v.w};
    #pragma unroll
    for (int i = 0; i < 4; ++i) {
        o[2 * i]     = __uint_as_float(u[i] << 16);
        o[2 * i + 1] = __uint_as_float(u[i] & 0xFFFF0000u);
    }
}

// ---------- shared xs body: NHWC bf16 of (x + up2(prev)) ----------
__device__ __forceinline__ void xs_body(void* smem,
    const float* __restrict__ x, const float* __restrict__ prev,
    ushort* __restrict__ xs, int H, int W, int bx, int by, int bz)
{
    ushort (*tile)[72] = (ushort(*)[72])smem;
    const int HW = H * W, W2 = W >> 1;
    int b = bz, c0 = by * 32, hw0 = bx * 64;
    const float* xb = x + ((size_t)b * 256 + c0) * HW;
    const float* pb = prev ? prev + ((size_t)b * 256 + c0) * (HW >> 2) : nullptr;

    int hwl = threadIdx.x & 63, cl0 = threadIdx.x >> 6;
    int hw = hw0 + hwl;
    bool ok = hw < HW;
    int hwc = ok ? hw : HW - 1;
    int h = hwc / W, w = hwc - h * W;
    int pidx = (h >> 1) * W2 + (w >> 1);
    #pragma unroll
    for (int p = 0; p < 8; ++p) {
        int cl = p * 4 + cl0;
        float v = 0.f;
        if (ok) {
            v = xb[(size_t)cl * HW + hw];
            if (pb) v += pb[(size_t)cl * (HW >> 2) + pidx];
        }
        tile[cl][hwl] = f2bf(v);
    }
    __syncthreads();
    int hwl2 = threadIdx.x >> 2, cc = (threadIdx.x & 3) * 8;
    int hw2 = hw0 + hwl2;
    if (hw2 < HW) {
        ushort vals[8];
        #pragma unroll
        for (int j = 0; j < 8; ++j) vals[j] = tile[cc + j][hwl2];
        *(uint4*)&xs[((size_t)b * HW + hw2) * 256 + c0 + cc] = *(uint4*)vals;
    }
}

// ---------- prolog: weight cvt (y=0..6) + bias prefill (y=7..9) + zero (y=10) + xs3 (y=11) ----------
struct ProArgs {
    const float* wsrc[7];
    ushort*      wdst[7];
    float*       outp[3];      // lvl1..3 bias-prefill targets
    const float* bias[3];
    int          HW[3];
    float*       zbase;
    int          z4;
    const float* x3;
    ushort*      xs3;
};
__global__ __launch_bounds__(256) void prolog_kernel(ProArgs a) {
    __shared__ __align__(16) char smem[32 * 72 * 2];
    int y = blockIdx.y;
    if (y < 7) {
        int M = (y < 4) ? 256 : 27;
        int idx = blockIdx.x * 256 + threadIdx.x;    // m*288 + r*32 + c8
        if (idx < M * 288) {
            int m = idx / 288, rem = idx - m * 288;
            int r = rem >> 5, c8 = rem & 31;
            const float* s = a.wsrc[y] + ((size_t)(m * 256 + c8 * 8)) * 9 + r;
            ushort vals[8];
            #pragma unroll
            for (int j = 0; j < 8; ++j) vals[j] = f2bf(s[j * 9]);
            *(uint4*)&a.wdst[y][(size_t)m * 2304 + r * 256 + c8 * 8] = *(uint4*)vals;
        }
    } else if (y < 10) {
        int t = y - 7;
        int HW = a.HW[t];
        int i = blockIdx.x * 256 + threadIdx.x;
        if (i < 128 * HW) {
            int e = i << 2;
            int m = (e / HW) & 255;
            float v = a.bias[t][m];
            *(float4*)&a.outp[t][e] = float4{v, v, v, v};
        }
    } else if (y == 10) {
        int i = blockIdx.x * 256 + threadIdx.x;
        if (i < a.z4) ((float4*)a.zbase)[i] = float4{0.f, 0.f, 0.f, 0.f};
    } else {
        int vb = blockIdx.x;
        if (vb < 48)
            xs_body(smem, a.x3, nullptr, a.xs3, 12, 12, vb % 3, (vb / 3) & 7, vb / 24);
    }
}

// ---------- xs kernel (levels 2,1,0) ----------
__global__ __launch_bounds__(256) void xs_nhwc(
    const float* __restrict__ x, const float* __restrict__ prev,
    ushort* __restrict__ xs, int H, int W)
{
    __shared__ __align__(16) char smem[32 * 72 * 2];
    xs_body(smem, x, prev, xs, H, W, blockIdx.x, blockIdx.y, blockIdx.z);
}

// ---------- offset conv: bf16 MFMA, M=27 (pad 32), split-K, dbuf ----------
__global__ __launch_bounds__(256) void off_mfma(
    const ushort* __restrict__ A, const ushort* __restrict__ xs,
    const ushort* __restrict__ zeros, float* __restrict__ offbuf,
    int N, int H, int W, int ktiles)
{
    __shared__ __align__(16) ushort As[2][32 * 32];
    __shared__ __align__(16) ushort Bs[2][64 * 32];
    const int b  = blockIdx.z;
    const int n0 = blockIdx.x * 64;
    const int kt0 = blockIdx.y * ktiles * 32;
    const int tid = threadIdx.x, lane = tid & 63, wv = tid >> 6;
    const ushort* xb = xs + (size_t)b * N * 256;

    int n = n0 + (tid >> 2); if (n >= N) n = N - 1;
    int h = n / W, w = n - h * W;
    int kcc = (tid & 3) * 8;

    auto stage = [&](int kt, int bi) {
        int r = kt >> 8, c0k = kt & 255;
        int ry = r / 3 - 1, rx = r - (r / 3) * 3 - 1;
        if (tid < 128) {
            int row = tid >> 2; if (row > 26) row = 26;
            gload_lds16(A + (size_t)row * 2304 + kt + kcc,
                        (char*)As[bi] + (size_t)(tid & ~63) * 16);
        }
        int ih = h + ry, iw = w + rx;
        const ushort* src = (ih >= 0 && ih < H && iw >= 0 && iw < W)
            ? xb + (((size_t)(ih * W + iw)) << 8) + c0k + kcc
            : zeros;
        gload_lds16(src, (char*)Bs[bi] + (size_t)(tid & ~63) * 16);
    };

    f4 acc[2] = {};
    stage(kt0, 0);
    for (int kk = 0; kk < ktiles; ++kk) {
        __syncthreads();
        if (kk + 1 < ktiles) stage(kt0 + (kk + 1) * 32, (kk + 1) & 1);
        const ushort* as = As[kk & 1];
        const ushort* bs = Bs[kk & 1];
        bfrag bf = *(const bfrag*)&bs[(wv * 16 + (lane & 15)) * 32 + (lane >> 4) * 8];
        bfrag a0 = *(const bfrag*)&as[(lane & 15) * 32 + (lane >> 4) * 8];
        bfrag a1 = *(const bfrag*)&as[(16 + (lane & 15)) * 32 + (lane >> 4) * 8];
        acc[0] = __builtin_amdgcn_mfma_f32_16x16x32_bf16(a0, bf, acc[0], 0, 0, 0);
        acc[1] = __builtin_amdgcn_mfma_f32_16x16x32_bf16(a1, bf, acc[1], 0, 0, 0);
    }

    int nn = n0 + wv * 16 + (lane & 15);
    if (nn < N) {
        #pragma unroll
        for (int mb = 0; mb < 2; ++mb)
            #pragma unroll
            for (int t = 0; t < 4; ++t) {
                int m = mb * 16 + (lane >> 4) * 4 + t;
                if (m < 27)
                    atomicAdd(&offbuf[((size_t)b * 27 + m) * N + nn], acc[mb][t]);
            }
    }
}

// ---------- deformable sampling (NHWC) -> cols[b][hw][r*256+c] bf16 ----------
__global__ __launch_bounds__(256) void sampling_kernel(
    const ushort* __restrict__ xs, const float* __restrict__ off,
    const float* __restrict__ ob, ushort* __restrict__ cols,
    int H, int W)
{
    __shared__ float4 gw[32][9];
    __shared__ int4   go[32][9];
    const int HW = H * W;
    const int b = blockIdx.z;
    const int hw0 = blockIdx.x * 32;
    const int tid = threadIdx.x;
    const float* offb = off + (size_t)b * 27 * HW;
    const ushort* xb = xs + (size_t)b * HW * 256;

    for (int it = tid; it < 32 * 9; it += 256) {
        int hwl = it / 9, k = it - hwl * 9;
        int hw = hw0 + hwl; if (hw >= HW) hw = HW - 1;
        int h = hw / W, w = hw - h * W;
        float dy = offb[(size_t)(2 * k) * HW + hw] + ob[2 * k];
        float dx = offb[(size_t)(2 * k + 1) * HW + hw] + ob[2 * k + 1];
        float mv = offb[(size_t)(18 + k) * HW + hw] + ob[18 + k];
        float mk = 1.0f / (1.0f + __expf(-mv));
        float py = (float)h - 1.0f + (float)(k / 3) + dy;
        float px = (float)w - 1.0f + (float)(k % 3) + dx;
        float y0f = floorf(py), x0f = floorf(px);
        float wy = py - y0f, wx = px - x0f;
        int y0 = (int)y0f, x0i = (int)x0f;
        int y1 = y0 + 1, x1 = x0i + 1;
        bool vy0 = (y0 >= 0) & (y0 < H), vy1 = (y1 >= 0) & (y1 < H);
        bool vx0 = (x0i >= 0) & (x0i < W), vx1 = (x1 >= 0) & (x1 < W);
        float w00 = (1.f - wy) * (1.f - wx) * ((vy0 & vx0) ? mk : 0.f);
        float w01 = (1.f - wy) * wx        * ((vy0 & vx1) ? mk : 0.f);
        float w10 = wy * (1.f - wx)        * ((vy1 & vx0) ? mk : 0.f);
        float w11 = wy * wx                * ((vy1 & vx1) ? mk : 0.f);
        int cy0 = min(max(y0, 0), H - 1), cy1 = min(max(y1, 0), H - 1);
        int cx0 = min(max(x0i, 0), W - 1), cx1 = min(max(x1, 0), W - 1);
        gw[hwl][k] = float4{w00, w01, w10, w11};
        go[hwl][k] = int4{(cy0 * W + cx0) << 8, (cy0 * W + cx1) << 8,
                          (cy1 * W + cx0) << 8, (cy1 * W + cx1) << 8};
    }
    __syncthreads();

    int hwl = tid >> 3, cb = (tid & 7) * 32;
    int hw = hw0 + hwl;
    if (hw >= HW) return;
    ushort* colp = cols + ((size_t)b * HW + hw) * 2304 + cb;

    #pragma unroll
    for (int k = 0; k < 9; ++k) {
        float4 wv = gw[hwl][k];
        int4   ov = go[hwl][k];
        const ushort* p00 = xb + ov.x + cb;
        const ushort* p01 = xb + ov.y + cb;
        const ushort* p10 = xb + ov.z + cb;
        const ushort* p11 = xb + ov.w + cb;
        #pragma unroll
        for (int j = 0; j < 4; ++j) {
            float f00[8], f01[8], f10[8], f11[8];
            bf8_to_f(*(const uint4*)(p00 + 8 * j), f00);
            bf8_to_f(*(const uint4*)(p01 + 8 * j), f01);
            bf8_to_f(*(const uint4*)(p10 + 8 * j), f10);
            bf8_to_f(*(const uint4*)(p11 + 8 * j), f11);
            unsigned int pk[4];
            #pragma unroll
            for (int t = 0; t < 4; ++t) {
                float lo = f00[2 * t] * wv.x + f01[2 * t] * wv.y +
                           f10[2 * t] * wv.z + f11[2 * t] * wv.w;
                float hi = f00[2 * t + 1] * wv.x + f01[2 * t + 1] * wv.y +
                           f10[2 * t + 1] * wv.z + f11[2 * t + 1] * wv.w;
                pk[t] = (unsigned int)f2bf(lo) | ((unsigned int)f2bf(hi) << 16);
            }
            *(uint4*)(colp + k * 256 + 8 * j) = make_uint4(pk[0], pk[1], pk[2], pk[3]);
        }
    }
}

// ---------- bf16 MFMA GEMM: tile 128m x 64n, BK=64, DOUBLE-BUFFERED, swizzled ----
// LDS chunk (row, c) holds global K-chunk (c ^ (row&7)).
// grid: (ceil(N/64), 2*S, B); kchunk = 2304/S (multiple of 64).
template<bool IMPLICIT, bool SPLITK>
__global__ __launch_bounds__(256) void mfma_gemm(
    const ushort* __restrict__ A, const float* __restrict__ bias,
    const ushort* __restrict__ Bt, const ushort* __restrict__ zeros,
    float* __restrict__ outp, int N, int H, int W, int kchunk)
{
    __shared__ __align__(16) ushort As[2][128 * 64];
    __shared__ __align__(16) ushort Bs[2][64 * 64];
    const int b  = blockIdx.z;
    const int m0 = (blockIdx.y & 1) * 128;
    const int kt0 = (blockIdx.y >> 1) * kchunk;
    const int n0 = blockIdx.x * 64;
    const int tid  = threadIdx.x;
    const int lane = tid & 63;
    const int wv   = tid >> 6;
    const int wm = wv & 1, wn = wv >> 1;     // wave tile: 64m x 32n

    const ushort* Bb = IMPLICIT ? Bt + (size_t)b * N * 256
                                : Bt + (size_t)b * (size_t)N * 2304;

    // staging: thread i stages LDS chunk i (16B); global chunk = (i&7)^((i>>3)&7)
    const int sc8 = ((tid & 7) ^ ((tid >> 3) & 7)) * 8;
    const int srow = tid >> 3;               // 0..31
    int bn[2], bh[2], bw[2];
    #pragma unroll
    for (int j = 0; j < 2; ++j) {
        int n = n0 + j * 32 + srow; if (n >= N) n = N - 1;
        bn[j] = n; bh[j] = n / W; bw[j] = n - bh[j] * W;
    }

    auto stage = [&](int kt, int bi) {
        #pragma unroll
        for (int i = 0; i < 4; ++i) {
            gload_lds16(A + (size_t)(m0 + i * 32 + srow) * 2304 + kt + sc8,
                        (char*)As[bi] + (size_t)(i * 256 + (tid & ~63)) * 16);
        }
        if (!IMPLICIT) {
            #pragma unroll
            for (int j = 0; j < 2; ++j)
                gload_lds16(Bb + (size_t)bn[j] * 2304 + kt + sc8,
                            (char*)Bs[bi] + (size_t)(j * 256 + (tid & ~63)) * 16);
        } else {
            int r = kt >> 8, c0k = kt & 255;
            int ry = r / 3 - 1, rx = r - (r / 3) * 3 - 1;
            #pragma unroll
            for (int j = 0; j < 2; ++j) {
                int ih = bh[j] + ry, iw = bw[j] + rx;
                const ushort* src = (ih >= 0 && ih < H && iw >= 0 && iw < W)
                    ? Bb + (((size_t)(ih * W + iw)) << 8) + c0k + sc8
                    : zeros;
                gload_lds16(src, (char*)Bs[bi] + (size_t)(j * 256 + (tid & ~63)) * 16);
            }
        }
    };

    // fragment reads: row stride 64 elems (8 chunks); swizzle fv = lane&7
    const int fq = (lane >> 4);            // 0..3
    const int fv = (lane & 7);
    f4 acc[4][2] = {};

    const int nit = kchunk >> 6;
    stage(kt0, 0);
    for (int it = 0; it < nit; ++it) {
        __syncthreads();                    // drains buf[it&1]; overlapped prev consume
        if (it + 1 < nit) stage(kt0 + (it + 1) * 64, (it + 1) & 1);
        const ushort* as = As[it & 1];
        const ushort* bs = Bs[it & 1];
        bfrag af[2][4], bf[2][2];
        #pragma unroll
        for (int kh = 0; kh < 2; ++kh) {
            int ch = ((kh * 4 + fq) ^ fv) * 8;
            #pragma unroll
            for (int i = 0; i < 4; ++i)
                af[kh][i] = *(const bfrag*)&as[(wm * 64 + i * 16 + (lane & 15)) * 64 + ch];
            #pragma unroll
            for (int j = 0; j < 2; ++j)
                bf[kh][j] = *(const bfrag*)&bs[(wn * 32 + j * 16 + (lane & 15)) * 64 + ch];
        }
        #pragma unroll
        for (int kh = 0; kh < 2; ++kh)
            #pragma unroll
            for (int i = 0; i < 4; ++i)
                #pragma unroll
                for (int j = 0; j < 2; ++j)
                    acc[i][j] = __builtin_amdgcn_mfma_f32_16x16x32_bf16(
                        af[kh][i], bf[kh][j], acc[i][j], 0, 0, 0);
    }

    const int mb = m0 + wm * 64, nb = n0 + wn * 32;
    #pragma unroll
    for (int i = 0; i < 4; ++i) {
        int mrow = mb + i * 16 + (lane >> 4) * 4;
        #pragma unroll
        for (int j = 0; j < 2; ++j) {
            int n = nb + j * 16 + (lane & 15);
            if (n < N) {
                #pragma unroll
                for (int t = 0; t < 4; ++t) {
                    int m = mrow + t;
                    if (SPLITK)
                        atomicAdd(&outp[((size_t)b * 256 + m) * N + n], acc[i][j][t]);
                    else
                        outp[((size_t)b * 256 + m) * N + n] = acc[i][j][t] + bias[m];
                }
            }
        }
    }
}

// ---------- host launch ----------
extern "C" void kernel_launch(void* const* d_in, const int* in_sizes, int n_in,
                              void* d_out, int out_size, void* d_ws, size_t ws_size,
                              hipStream_t stream)
{
    const float* x[4]   = {(const float*)d_in[0], (const float*)d_in[1],
                           (const float*)d_in[2], (const float*)d_in[3]};
    const float* wgt[4] = {(const float*)d_in[4], (const float*)d_in[6],
                           (const float*)d_in[8], (const float*)d_in[10]};
    const float* bia[4] = {(const float*)d_in[5], (const float*)d_in[7],
                           (const float*)d_in[9], (const float*)d_in[11]};
    const float* owt[4] = {nullptr, (const float*)d_in[12],
                           (const float*)d_in[14], (const float*)d_in[16]};
    const float* obv[4] = {nullptr, (const float*)d_in[13],
                           (const float*)d_in[15], (const float*)d_in[17]};

    const int B = 2;
    const int Hs[4] = {96, 48, 24, 12};
    const int HWs[4] = {96 * 96, 48 * 48, 24 * 24, 12 * 12};

    float* out = (float*)d_out;
    size_t outOff[4];
    outOff[0] = 0;
    outOff[1] = outOff[0] + (size_t)B * 256 * HWs[0];
    outOff[2] = outOff[1] + (size_t)B * 256 * HWs[1];
    outOff[3] = outOff[2] + (size_t)B * 256 * HWs[2];

    // ---- ws carve (256B aligned)
    char* ws = (char*)d_ws;
    size_t off = 0;
    auto carve = [&](size_t bytes) { void* p = ws + off; off = (off + bytes + 255) & ~(size_t)255; return p; };
    ushort* wbf[4];
    ushort* owbf[4] = {nullptr, nullptr, nullptr, nullptr};
    for (int i = 0; i < 4; ++i) wbf[i] = (ushort*)carve((size_t)256 * 2304 * 2);
    for (int i = 1; i < 4; ++i) owbf[i] = (ushort*)carve((size_t)27 * 2304 * 2);
    ushort* cols = (ushort*)carve((size_t)B * HWs[1] * 2304 * 2);   // max: level 1
    ushort* xsb[4];
    for (int i = 0; i < 4; ++i) xsb[i] = (ushort*)carve((size_t)B * 256 * HWs[i] * 2);
    int offElems = B * 27 * (HWs[1] + HWs[2] + HWs[3]);
    float* offbase = (float*)carve((size_t)offElems * 4 + 1024);
    ushort* zeros = (ushort*)(offbase + offElems);   // 1 KB zero page
    float* offbuf[4] = {nullptr,
                        offbase,
                        offbase + (size_t)B * 27 * HWs[1],
                        offbase + (size_t)B * 27 * (HWs[1] + HWs[2])};

    // ---- prolog: weight cvt + bias prefill + zero + xs3, one launch
    {
        ProArgs a;
        a.wsrc[0] = wgt[0]; a.wsrc[1] = wgt[1]; a.wsrc[2] = wgt[2]; a.wsrc[3] = wgt[3];
        a.wsrc[4] = owt[1]; a.wsrc[5] = owt[2]; a.wsrc[6] = owt[3];
        a.wdst[0] = wbf[0]; a.wdst[1] = wbf[1]; a.wdst[2] = wbf[2]; a.wdst[3] = wbf[3];
        a.wdst[4] = owbf[1]; a.wdst[5] = owbf[2]; a.wdst[6] = owbf[3];
        for (int i = 0; i < 3; ++i) {
            a.outp[i] = out + outOff[i + 1]; a.bias[i] = bia[i + 1]; a.HW[i] = HWs[i + 1];
        }
        a.zbase = offbase;
        a.z4 = (offElems * 4 + 1024) / 16;
        a.x3 = x[3];
        a.xs3 = xsb[3];
        dim3 grd(1152, 12);      // x covers max of {cvt 288, fill 1152, zero 160, xs3 48}
        prolog_kernel<<<grd, 256, 0, stream>>>(a);
    }

    const int ktiles[4] = {0, 9, 6, 3};    // off-conv split-K chunking (BK=32)
    const int ksplit[4] = {1, 2, 6, 12};   // main-gemm split-K; 2304/S % 64 == 0

    for (int lvl = 3; lvl >= 1; --lvl) {
        int H = Hs[lvl], W = H, HW = HWs[lvl];

        // offset conv (bf16 MFMA split-K, NHWC implicit staging, dbuf)
        {
            dim3 grd((HW + 63) / 64, 72 / ktiles[lvl], B);
            off_mfma<<<grd, 256, 0, stream>>>(
                owbf[lvl], xsb[lvl], zeros, offbuf[lvl], HW, H, W, ktiles[lvl]);
        }
        // deformable sampling -> cols [b][hw][r*256+c]
        {
            dim3 grd((HW + 31) / 32, 1, B);
            sampling_kernel<<<grd, 256, 0, stream>>>(
                xsb[lvl], offbuf[lvl], obv[lvl], cols, H, W);
        }
        // main conv: split-K MFMA GEMM into bias-prefilled out
        {
            dim3 grd((HW + 63) / 64, 2 * ksplit[lvl], B);
            mfma_gemm<false, true><<<grd, 256, 0, stream>>>(
                wbf[lvl], bia[lvl], cols, zeros, out + outOff[lvl],
                HW, H, W, 2304 / ksplit[lvl]);
        }
        // xs for next-finer level
        {
            int Hn = Hs[lvl - 1];
            dim3 grd((HWs[lvl - 1] + 63) / 64, 8, B);
            xs_nhwc<<<grd, 256, 0, stream>>>(
                x[lvl - 1], out + outOff[lvl], xsb[lvl - 1], Hn, Hn);
        }
    }

    // level 0: implicit NHWC MFMA GEMM, direct bias write (no split-K)
    {
        dim3 grd((HWs[0] + 63) / 64, 2, B);
        mfma_gemm<true, false><<<grd, 256, 0, stream>>>(
            wbf[0], bia[0], xsb[0], zeros, out + outOff[0],
            HWs[0], Hs[0], Hs[0], 2304);
    }
}